// Round 1
// baseline (2098.124 us; speedup 1.0000x reference)
//
#include <hip/hip_runtime.h>
#include <math.h>

static constexpr float EPS_SK = 0.02f;
static constexpr float LOG2E  = 1.4426950408889634f;
static constexpr float LN2F   = 0.6931471805599453f;

__device__ __forceinline__ float fexp2(float x){ return __builtin_amdgcn_exp2f(x); }
__device__ __forceinline__ float flog2(float x){ return __builtin_amdgcn_logf(x); }

// ---------------- FPS: one block per batch, 512 threads, points in LDS ----------------
__global__ __launch_bounds__(512) void fps_kernel(const float* __restrict__ gt,
                                                  float* __restrict__ gt_fps) {
  __shared__ float sx[4096], sy[4096], sz[4096];
  __shared__ int   sidx[1024];
  __shared__ float rv[8];
  __shared__ int   ri[8];
  __shared__ int   swin;
  const int b = blockIdx.x;
  const int t = threadIdx.x;
  const float* P = gt + (size_t)b*4096*3;
  for (int i = t; i < 4096; i += 512) {
    sx[i] = P[i*3+0]; sy[i] = P[i*3+1]; sz[i] = P[i*3+2];
  }
  __syncthreads();
  float px[8], py[8], pz[8], dst[8];
#pragma unroll
  for (int j = 0; j < 8; ++j) {
    int i = t + j*512;
    px[j] = sx[i]; py[j] = sy[i]; pz[j] = sz[i];
    dst[j] = 1e10f;  // matches reference init 10000000000.0
  }
  if (t == 0) sidx[0] = 0;
  const int lane = t & 63;
  const int wv   = t >> 6;
  int widx = 0;
  for (int s = 1; s < 1024; ++s) {
    float cx = sx[widx], cy = sy[widx], cz = sz[widx];
    float bv = -1.0f; int bi = 0x7fffffff;
    {
#pragma clang fp contract(off)
#pragma unroll
      for (int j = 0; j < 8; ++j) {
        float dx = px[j]-cx, dy = py[j]-cy, dz = pz[j]-cz;
        float d  = dx*dx + dy*dy + dz*dz;
        float nd = fminf(dst[j], d);
        dst[j] = nd;
        // indices ascend with j for fixed t, so strict > keeps first occurrence
        if (nd > bv) { bv = nd; bi = t + j*512; }
      }
    }
    // wave argmax butterfly (first-index tie-break)
#pragma unroll
    for (int off = 32; off >= 1; off >>= 1) {
      float ov = __shfl_xor(bv, off, 64);
      int   oi = __shfl_xor(bi, off, 64);
      if (ov > bv || (ov == bv && oi < bi)) { bv = ov; bi = oi; }
    }
    if (lane == 0) { rv[wv] = bv; ri[wv] = bi; }
    __syncthreads();
    if (t == 0) {
      float v = rv[0]; int i0 = ri[0];
#pragma unroll
      for (int w = 1; w < 8; ++w) {
        if (rv[w] > v || (rv[w] == v && ri[w] < i0)) { v = rv[w]; i0 = ri[w]; }
      }
      swin = i0; sidx[s] = i0;
    }
    __syncthreads();
    widx = swin;
  }
  // gather gt_fps
  for (int i = t; i < 1024; i += 512) {
    int id = sidx[i];
    float* o = gt_fps + (size_t)(b*1024 + i)*3;
    o[0] = sx[id]; o[1] = sy[id]; o[2] = sz[id];
  }
}

// ---------------- x_tiled prep: (2,1024,3) = coarse tiled 2x ----------------
__global__ __launch_bounds__(256) void prep_xtile(const float* __restrict__ coarse,
                                                  float* __restrict__ xt) {
  int i = blockIdx.x*256 + threadIdx.x;
  if (i >= 2*1024*3) return;
  int b = i / 3072; int r = (i % 3072) / 3; int c = i % 3;
  xt[i] = coarse[(size_t)(b*512 + (r & 511))*3 + c];
}

// ---------------- EMD Sinkhorn pass: row-wise online LSE, cols tiled in LDS ----------------
#define EMD_TM 1024
__global__ __launch_bounds__(256) void emd_pass(const float* __restrict__ xpts,
                                                const float* __restrict__ ypts,
                                                const float* __restrict__ vin,
                                                float* __restrict__ vout,
                                                int N, float logN, int use_vin,
                                                int k, const int* __restrict__ itersPtr) {
  if (k >= *itersPtr) return;
  __shared__ float tyx[EMD_TM], tyy[EMD_TM], tyz[EMD_TM], tg[EMD_TM];
  const int b = blockIdx.y;
  const int t = threadIdx.x;
  const int lane = t & 63;
  const int wv   = t >> 6;
  const int r0 = blockIdx.x*32 + wv*8;
  float px[8], py[8], pz[8], mx[8], sm[8];
#pragma unroll
  for (int j = 0; j < 8; ++j) {
    const float* xp = xpts + (size_t)(b*N + r0 + j)*3;
    px[j] = xp[0]; py[j] = xp[1]; pz[j] = xp[2];
    mx[j] = -3.4e38f; sm[j] = 0.0f;
  }
  const float S = LOG2E / EPS_SK;
  const int ntiles = N / EMD_TM;
  for (int tt = 0; tt < ntiles; ++tt) {
    const int base = tt*EMD_TM;
    __syncthreads();
    for (int i = t; i < EMD_TM; i += 256) {
      const float* yp = ypts + (size_t)(b*N + base + i)*3;
      tyx[i] = yp[0]; tyy[i] = yp[1]; tyz[i] = yp[2];
      tg[i]  = use_vin ? vin[b*N + base + i] : 0.0f;
    }
    __syncthreads();
    for (int mi = lane; mi < EMD_TM; mi += 64) {
      float yx = tyx[mi], yy = tyy[mi], yz = tyz[mi], g = tg[mi];
#pragma unroll
      for (int j = 0; j < 8; ++j) {
        float dx = px[j]-yx, dy = py[j]-yy, dz = pz[j]-yz;
        float d  = dx*dx + dy*dy + dz*dz;
        float tv = (g - d) * S;          // (g - C)/eps in log2 domain
        float nm = fmaxf(mx[j], tv);
        sm[j] = sm[j]*fexp2(mx[j]-nm) + fexp2(tv-nm);
        mx[j] = nm;
      }
    }
  }
#pragma unroll
  for (int j = 0; j < 8; ++j) {
#pragma unroll
    for (int off = 1; off < 64; off <<= 1) {
      float om = __shfl_xor(mx[j], off, 64);
      float os = __shfl_xor(sm[j], off, 64);
      float nm = fmaxf(mx[j], om);
      sm[j] = sm[j]*fexp2(mx[j]-nm) + os*fexp2(om-nm);
      mx[j] = nm;
    }
  }
  if (lane == 0) {
#pragma unroll
    for (int j = 0; j < 8; ++j) {
      float lse = (mx[j] + flog2(sm[j])) * LN2F;   // natural-log LSE
      vout[b*N + r0 + j] = -EPS_SK * (lse + logN);
    }
  }
}

// ---------------- EMD final: d[n] = sum_m softmax((g-C)/eps) * C, write sqrt ----------------
__global__ __launch_bounds__(256) void emd_final(const float* __restrict__ xpts,
                                                 const float* __restrict__ ypts,
                                                 const float* __restrict__ gin,
                                                 float* __restrict__ dout,
                                                 int N, const int* __restrict__ itersPtr) {
  const int use_g = (*itersPtr > 0) ? 1 : 0;
  __shared__ float tyx[EMD_TM], tyy[EMD_TM], tyz[EMD_TM], tg[EMD_TM];
  const int b = blockIdx.y;
  const int t = threadIdx.x;
  const int lane = t & 63;
  const int wv   = t >> 6;
  const int r0 = blockIdx.x*32 + wv*8;
  float px[8], py[8], pz[8], mx[8], sm[8], wc[8];
#pragma unroll
  for (int j = 0; j < 8; ++j) {
    const float* xp = xpts + (size_t)(b*N + r0 + j)*3;
    px[j] = xp[0]; py[j] = xp[1]; pz[j] = xp[2];
    mx[j] = -3.4e38f; sm[j] = 0.0f; wc[j] = 0.0f;
  }
  const float S = LOG2E / EPS_SK;
  const int ntiles = N / EMD_TM;
  for (int tt = 0; tt < ntiles; ++tt) {
    const int base = tt*EMD_TM;
    __syncthreads();
    for (int i = t; i < EMD_TM; i += 256) {
      const float* yp = ypts + (size_t)(b*N + base + i)*3;
      tyx[i] = yp[0]; tyy[i] = yp[1]; tyz[i] = yp[2];
      tg[i]  = use_g ? gin[b*N + base + i] : 0.0f;
    }
    __syncthreads();
    for (int mi = lane; mi < EMD_TM; mi += 64) {
      float yx = tyx[mi], yy = tyy[mi], yz = tyz[mi], g = tg[mi];
#pragma unroll
      for (int j = 0; j < 8; ++j) {
        float dx = px[j]-yx, dy = py[j]-yy, dz = pz[j]-yz;
        float d  = dx*dx + dy*dy + dz*dz;
        float tv = (g - d) * S;
        float nm = fmaxf(mx[j], tv);
        float r  = fexp2(mx[j]-nm);
        float e  = fexp2(tv-nm);
        sm[j] = sm[j]*r + e;
        wc[j] = wc[j]*r + e*d;
        mx[j] = nm;
      }
    }
  }
#pragma unroll
  for (int j = 0; j < 8; ++j) {
#pragma unroll
    for (int off = 1; off < 64; off <<= 1) {
      float om = __shfl_xor(mx[j], off, 64);
      float os = __shfl_xor(sm[j], off, 64);
      float ow = __shfl_xor(wc[j], off, 64);
      float nm = fmaxf(mx[j], om);
      float r1 = fexp2(mx[j]-nm);
      float r2 = fexp2(om-nm);
      sm[j] = sm[j]*r1 + os*r2;
      wc[j] = wc[j]*r1 + ow*r2;
      mx[j] = nm;
    }
  }
  if (lane == 0) {
#pragma unroll
    for (int j = 0; j < 8; ++j) {
      dout[b*N + r0 + j] = sqrtf(wc[j] / sm[j]);
    }
  }
}

// ---------------- mean over N per batch ----------------
__global__ __launch_bounds__(256) void reduce_mean(const float* __restrict__ v, int N,
                                                   float* __restrict__ out) {
  __shared__ float lds[4];
  int b = blockIdx.x;
  float s = 0.0f;
  for (int i = threadIdx.x; i < N; i += 256) s += v[b*N + i];
#pragma unroll
  for (int off = 32; off >= 1; off >>= 1) s += __shfl_xor(s, off, 64);
  int lane = threadIdx.x & 63, wv = threadIdx.x >> 6;
  if (lane == 0) lds[wv] = s;
  __syncthreads();
  if (threadIdx.x == 0) out[b] = (lds[0]+lds[1]+lds[2]+lds[3]) / (float)N;
}

// ---------------- chamfer: per-query min over target chunk, atomicMin on uint bits ----------------
__global__ __launch_bounds__(256) void cham_min(const float* __restrict__ qpts, int nq,
                                                const float* __restrict__ tpts, int nt,
                                                unsigned* __restrict__ outmin, int chunk) {
  __shared__ float tx[1024], ty[1024], tz[1024];
  const int b  = blockIdx.z;
  const int qi = blockIdx.x*256 + threadIdx.x;
  const int cb = blockIdx.y * chunk;
  for (int i = threadIdx.x; i < chunk; i += 256) {
    const float* tp = tpts + (size_t)(b*nt + cb + i)*3;
    tx[i] = tp[0]; ty[i] = tp[1]; tz[i] = tp[2];
  }
  __syncthreads();
  const float* qp = qpts + (size_t)(b*nq + qi)*3;
  float qx = qp[0], qy = qp[1], qz = qp[2];
  float m = 3.4e38f;
  for (int i = 0; i < chunk; ++i) {
    float dx = qx-tx[i], dy = qy-ty[i], dz = qz-tz[i];
    float d = dx*dx + dy*dy + dz*dz;
    m = fminf(m, d);
  }
  atomicMin(&outmin[b*nq + qi], __float_as_uint(m));  // nonneg floats: uint order == float order
}

__device__ __forceinline__ float blk_sum(float v, float* lds) {
#pragma unroll
  for (int off = 32; off >= 1; off >>= 1) v += __shfl_xor(v, off, 64);
  int lane = threadIdx.x & 63, wv = threadIdx.x >> 6;
  __syncthreads();
  if (lane == 0) lds[wv] = v;
  __syncthreads();
  return lds[0]+lds[1]+lds[2]+lds[3];
}

__global__ __launch_bounds__(256) void cham_finalize(const unsigned* __restrict__ A,
                                                     const unsigned* __restrict__ B,
                                                     const unsigned* __restrict__ C,
                                                     const unsigned* __restrict__ D,
                                                     float* __restrict__ out) {
  __shared__ float lds[4];
  int b = blockIdx.x;
  float rA=0, sA=0, rB=0, sB=0, rC=0, sC=0, rD=0, sD=0;
  for (int i = threadIdx.x; i < 4096; i += 256) { float v = __uint_as_float(A[b*4096+i]); rA += v; sA += sqrtf(v); }
  rA = blk_sum(rA, lds); sA = blk_sum(sA, lds);
  for (int i = threadIdx.x; i < 512;  i += 256) { float v = __uint_as_float(B[b*512+i]);  rB += v; sB += sqrtf(v); }
  rB = blk_sum(rB, lds); sB = blk_sum(sB, lds);
  for (int i = threadIdx.x; i < 4096; i += 256) { float v = __uint_as_float(C[b*4096+i]); rC += v; sC += sqrtf(v); }
  rC = blk_sum(rC, lds); sC = blk_sum(sC, lds);
  for (int i = threadIdx.x; i < 4096; i += 256) { float v = __uint_as_float(D[b*4096+i]); rD += v; sD += sqrtf(v); }
  rD = blk_sum(rD, lds); sD = blk_sum(sD, lds);
  if (threadIdx.x == 0) {
    out[27652 + b] = 0.5f*(sA/4096.0f + sB/512.0f);   // cd1_p
    out[27654 + b] = 0.5f*(sC/4096.0f + sD/4096.0f);  // cd2_p
    out[27656 + b] = rA/4096.0f + rB/512.0f;          // cd1_t
    out[27658 + b] = rC/4096.0f + rD/4096.0f;         // cd2_t
  }
}

extern "C" void kernel_launch(void* const* d_in, const int* in_sizes, int n_in,
                              void* d_out, int out_size, void* d_ws, size_t ws_size,
                              hipStream_t stream) {
  (void)in_sizes; (void)n_in; (void)out_size; (void)ws_size;
  const float* coarse = (const float*)d_in[0];
  const float* fine   = (const float*)d_in[1];
  const float* gt     = (const float*)d_in[2];
  const int*   iters  = (const int*)d_in[3];
  float* out = (float*)d_out;
  float* ws  = (float*)d_ws;

  float* chamA = ws + 0;        // 2*4096  gt->coarse
  float* chamB = ws + 8192;     // 2*512   coarse->gt
  float* chamC = ws + 9216;     // 2*4096  gt->fine
  float* chamD = ws + 17408;    // 2*4096  fine->gt
  float* fvec  = ws + 25600;    // 2*4096
  float* gvec  = ws + 33792;    // 2*4096
  float* dvec  = ws + 41984;    // 2*4096
  float* gtfps = ws + 50176;    // 2*1024*3
  float* xtile = ws + 56320;    // 2*1024*3

  hipMemsetAsync(ws, 0x7f, 25600*sizeof(float), stream);  // chamfer mins -> 3.39e38
  hipMemcpyAsync(out,        coarse, 3072*sizeof(float),  hipMemcpyDeviceToDevice, stream);
  hipMemcpyAsync(out + 3072, fine,   24576*sizeof(float), hipMemcpyDeviceToDevice, stream);

  prep_xtile<<<24, 256, 0, stream>>>(coarse, xtile);
  fps_kernel<<<2, 512, 0, stream>>>(gt, gtfps);

  const float logN1 = logf(1024.0f), logN2 = logf(4096.0f);
  // EMD1: x = tiled coarse (1024), y = gt_fps (1024)
  for (int k = 0; k < 4; ++k) {
    emd_pass<<<dim3(32,2), 256, 0, stream>>>(xtile, gtfps, gvec, fvec, 1024, logN1, k>0 ? 1 : 0, k, iters);
    emd_pass<<<dim3(32,2), 256, 0, stream>>>(gtfps, xtile, fvec, gvec, 1024, logN1, 1, k, iters);
  }
  emd_final<<<dim3(32,2), 256, 0, stream>>>(xtile, gtfps, gvec, dvec, 1024, iters);
  reduce_mean<<<2, 256, 0, stream>>>(dvec, 1024, out + 27648);  // emd1
  // EMD2: x = fine (4096), y = gt (4096)
  for (int k = 0; k < 4; ++k) {
    emd_pass<<<dim3(128,2), 256, 0, stream>>>(fine, gt, gvec, fvec, 4096, logN2, k>0 ? 1 : 0, k, iters);
    emd_pass<<<dim3(128,2), 256, 0, stream>>>(gt, fine, fvec, gvec, 4096, logN2, 1, k, iters);
  }
  emd_final<<<dim3(128,2), 256, 0, stream>>>(fine, gt, gvec, dvec, 4096, iters);
  reduce_mean<<<2, 256, 0, stream>>>(dvec, 4096, out + 27650);  // emd2

  // chamfer
  cham_min<<<dim3(16,1,2), 256, 0, stream>>>(gt,     4096, coarse, 512,  (unsigned*)chamA, 512);
  cham_min<<<dim3(2,4,2),  256, 0, stream>>>(coarse, 512,  gt,     4096, (unsigned*)chamB, 1024);
  cham_min<<<dim3(16,4,2), 256, 0, stream>>>(gt,     4096, fine,   4096, (unsigned*)chamC, 1024);
  cham_min<<<dim3(16,4,2), 256, 0, stream>>>(fine,   4096, gt,     4096, (unsigned*)chamD, 1024);
  cham_finalize<<<2, 256, 0, stream>>>((unsigned*)chamA, (unsigned*)chamB, (unsigned*)chamC, (unsigned*)chamD, out);
}

// Round 2
// 1792.431 us; speedup vs baseline: 1.1705x; 1.1705x over previous
//
#include <hip/hip_runtime.h>
#include <math.h>

static constexpr float EPS_SK = 0.02f;
static constexpr float LOG2E  = 1.4426950408889634f;
static constexpr float LN2F   = 0.6931471805599453f;

__device__ __forceinline__ float fexp2(float x){ return __builtin_amdgcn_exp2f(x); }
__device__ __forceinline__ float flog2(float x){ return __builtin_amdgcn_logf(x); }

// ---------------- FPS: one block per batch, 512 threads (8 waves), 8 pts/lane ----------------
// Critical-path redesign: 1 barrier/iter, parity double-buffered wave results,
// all-thread redundant 8-way reduce (no serial t0 phase, no second barrier).
__global__ __launch_bounds__(512) void fps_kernel(const float* __restrict__ gt,
                                                  float* __restrict__ gt_fps) {
  __shared__ __align__(16) float4 sp[4096];          // 64 KB points (w unused)
  __shared__ __align__(16) float  rv[2][8];
  __shared__ __align__(16) int    ri[2][8];
  const int b = blockIdx.x;
  const int t = threadIdx.x;
  const int lane = t & 63;
  const int wv   = t >> 6;
  const float* P = gt + (size_t)b*4096*3;
  for (int i = t; i < 4096; i += 512) {
    sp[i] = make_float4(P[i*3+0], P[i*3+1], P[i*3+2], 0.0f);
  }
  __syncthreads();
  float px[8], py[8], pz[8], dst[8];
#pragma unroll
  for (int j = 0; j < 8; ++j) {
    float4 q = sp[t + j*512];
    px[j] = q.x; py[j] = q.y; pz[j] = q.z;
    dst[j] = 1e10f;  // matches reference init 10000000000.0
  }
  float cx, cy, cz;
  { float4 q = sp[0]; cx = q.x; cy = q.y; cz = q.z; }
  if (t == 0) {
    float* o = gt_fps + (size_t)b*3072;
    o[0] = cx; o[1] = cy; o[2] = cz;
  }
  for (int s = 1; s < 1024; ++s) {
    float bv = -1.0f; int bj = 0;
    {
#pragma clang fp contract(off)
#pragma unroll
      for (int j = 0; j < 8; ++j) {
        float dx = px[j]-cx, dy = py[j]-cy, dz = pz[j]-cz;
        float d  = dx*dx + dy*dy + dz*dz;
        float nd = fminf(dst[j], d);
        dst[j] = nd;
        // indices ascend with j for fixed t, so strict > keeps first occurrence
        if (nd > bv) { bv = nd; bj = j; }
      }
    }
    int bi = t + bj*512;
    // wave argmax butterfly (first-index tie-break)
#pragma unroll
    for (int off = 32; off >= 1; off >>= 1) {
      float ov = __shfl_xor(bv, off, 64);
      int   oi = __shfl_xor(bi, off, 64);
      if (ov > bv || (ov == bv && oi < bi)) { bv = ov; bi = oi; }
    }
    const int pb = s & 1;
    if (lane == 0) { rv[pb][wv] = bv; ri[pb][wv] = bi; }
    __syncthreads();
    // every thread reduces the 8 wave results (vector LDS loads, no 2nd barrier)
    float4 v0 = *(const float4*)&rv[pb][0];
    float4 v1 = *(const float4*)&rv[pb][4];
    int4   i0 = *(const int4*)  &ri[pb][0];
    int4   i1 = *(const int4*)  &ri[pb][4];
    float vb = v0.x; int ib = i0.x;
    if (v0.y > vb || (v0.y == vb && i0.y < ib)) { vb = v0.y; ib = i0.y; }
    if (v0.z > vb || (v0.z == vb && i0.z < ib)) { vb = v0.z; ib = i0.z; }
    if (v0.w > vb || (v0.w == vb && i0.w < ib)) { vb = v0.w; ib = i0.w; }
    if (v1.x > vb || (v1.x == vb && i1.x < ib)) { vb = v1.x; ib = i1.x; }
    if (v1.y > vb || (v1.y == vb && i1.y < ib)) { vb = v1.y; ib = i1.y; }
    if (v1.z > vb || (v1.z == vb && i1.z < ib)) { vb = v1.z; ib = i1.z; }
    if (v1.w > vb || (v1.w == vb && i1.w < ib)) { vb = v1.w; ib = i1.w; }
    float4 q = sp[ib];
    cx = q.x; cy = q.y; cz = q.z;
    if (t == 0) {
      float* o = gt_fps + (size_t)b*3072 + s*3;
      o[0] = q.x; o[1] = q.y; o[2] = q.z;
    }
  }
}

// ---------------- x_tiled prep: (2,1024,3) = coarse tiled 2x ----------------
__global__ __launch_bounds__(256) void prep_xtile(const float* __restrict__ coarse,
                                                  float* __restrict__ xt) {
  int i = blockIdx.x*256 + threadIdx.x;
  if (i >= 2*1024*3) return;
  int b = i / 3072; int r = (i % 3072) / 3; int c = i % 3;
  xt[i] = coarse[(size_t)(b*512 + (r & 511))*3 + c];
}

// ---------------- merged EMD Sinkhorn pass (EMD1 N=1024 + EMD2 N=4096) ----------------
#define EMD_TM 1024
__device__ __forceinline__ void emd_pass_body(const float* __restrict__ xpts,
                                              const float* __restrict__ ypts,
                                              const float* __restrict__ vin,
                                              float* __restrict__ vout,
                                              int N, float logN, int use_vin,
                                              int b, int bx,
                                              float* tyx, float* tyy, float* tyz, float* tg) {
  const int t = threadIdx.x;
  const int lane = t & 63;
  const int wv   = t >> 6;
  const int r0 = bx*32 + wv*8;
  float px[8], py[8], pz[8], mx[8], sm[8];
#pragma unroll
  for (int j = 0; j < 8; ++j) {
    const float* xp = xpts + (size_t)(b*N + r0 + j)*3;
    px[j] = xp[0]; py[j] = xp[1]; pz[j] = xp[2];
    mx[j] = -3.4e38f; sm[j] = 0.0f;
  }
  const float S = LOG2E / EPS_SK;
  const int ntiles = N / EMD_TM;
  for (int tt = 0; tt < ntiles; ++tt) {
    const int base = tt*EMD_TM;
    __syncthreads();
    for (int i = t; i < EMD_TM; i += 256) {
      const float* yp = ypts + (size_t)(b*N + base + i)*3;
      tyx[i] = yp[0]; tyy[i] = yp[1]; tyz[i] = yp[2];
      tg[i]  = use_vin ? vin[b*N + base + i] : 0.0f;
    }
    __syncthreads();
    for (int mi = lane; mi < EMD_TM; mi += 64) {
      float yx = tyx[mi], yy = tyy[mi], yz = tyz[mi], g = tg[mi];
#pragma unroll
      for (int j = 0; j < 8; ++j) {
        float dx = px[j]-yx, dy = py[j]-yy, dz = pz[j]-yz;
        float d  = dx*dx + dy*dy + dz*dz;
        float tv = (g - d) * S;          // (g - C)/eps in log2 domain
        float nm = fmaxf(mx[j], tv);
        sm[j] = sm[j]*fexp2(mx[j]-nm) + fexp2(tv-nm);
        mx[j] = nm;
      }
    }
  }
#pragma unroll
  for (int j = 0; j < 8; ++j) {
#pragma unroll
    for (int off = 1; off < 64; off <<= 1) {
      float om = __shfl_xor(mx[j], off, 64);
      float os = __shfl_xor(sm[j], off, 64);
      float nm = fmaxf(mx[j], om);
      sm[j] = sm[j]*fexp2(mx[j]-nm) + os*fexp2(om-nm);
      mx[j] = nm;
    }
  }
  if (lane == 0) {
#pragma unroll
    for (int j = 0; j < 8; ++j) {
      float lse = (mx[j] + flog2(sm[j])) * LN2F;   // natural-log LSE
      vout[b*N + r0 + j] = -EPS_SK * (lse + logN);
    }
  }
}

__global__ __launch_bounds__(256) void emd_pass2(const float* __restrict__ x1, const float* __restrict__ y1,
                                                 const float* __restrict__ v1in, float* __restrict__ v1out,
                                                 const float* __restrict__ x2, const float* __restrict__ y2,
                                                 const float* __restrict__ v2in, float* __restrict__ v2out,
                                                 int use_vin, int k, const int* __restrict__ itersPtr) {
  if (k >= *itersPtr) return;
  __shared__ float tyx[EMD_TM], tyy[EMD_TM], tyz[EMD_TM], tg[EMD_TM];
  const int b = blockIdx.y;
  const int bx = blockIdx.x;
  if (bx < 32) {
    emd_pass_body(x1, y1, v1in, v1out, 1024, 6.931471805599453f /*log 1024*/, use_vin, b, bx, tyx, tyy, tyz, tg);
  } else {
    emd_pass_body(x2, y2, v2in, v2out, 4096, 8.317766166719343f /*log 4096*/, use_vin, b, bx-32, tyx, tyy, tyz, tg);
  }
}

// ---------------- merged EMD final: d[n] = sum_m softmax((g-C)/eps) * C, write sqrt ----------------
__device__ __forceinline__ void emd_final_body(const float* __restrict__ xpts,
                                               const float* __restrict__ ypts,
                                               const float* __restrict__ gin,
                                               float* __restrict__ dout,
                                               int N, int use_g, int b, int bx,
                                               float* tyx, float* tyy, float* tyz, float* tg) {
  const int t = threadIdx.x;
  const int lane = t & 63;
  const int wv   = t >> 6;
  const int r0 = bx*32 + wv*8;
  float px[8], py[8], pz[8], mx[8], sm[8], wc[8];
#pragma unroll
  for (int j = 0; j < 8; ++j) {
    const float* xp = xpts + (size_t)(b*N + r0 + j)*3;
    px[j] = xp[0]; py[j] = xp[1]; pz[j] = xp[2];
    mx[j] = -3.4e38f; sm[j] = 0.0f; wc[j] = 0.0f;
  }
  const float S = LOG2E / EPS_SK;
  const int ntiles = N / EMD_TM;
  for (int tt = 0; tt < ntiles; ++tt) {
    const int base = tt*EMD_TM;
    __syncthreads();
    for (int i = t; i < EMD_TM; i += 256) {
      const float* yp = ypts + (size_t)(b*N + base + i)*3;
      tyx[i] = yp[0]; tyy[i] = yp[1]; tyz[i] = yp[2];
      tg[i]  = use_g ? gin[b*N + base + i] : 0.0f;
    }
    __syncthreads();
    for (int mi = lane; mi < EMD_TM; mi += 64) {
      float yx = tyx[mi], yy = tyy[mi], yz = tyz[mi], g = tg[mi];
#pragma unroll
      for (int j = 0; j < 8; ++j) {
        float dx = px[j]-yx, dy = py[j]-yy, dz = pz[j]-yz;
        float d  = dx*dx + dy*dy + dz*dz;
        float tv = (g - d) * S;
        float nm = fmaxf(mx[j], tv);
        float r  = fexp2(mx[j]-nm);
        float e  = fexp2(tv-nm);
        sm[j] = sm[j]*r + e;
        wc[j] = wc[j]*r + e*d;
        mx[j] = nm;
      }
    }
  }
#pragma unroll
  for (int j = 0; j < 8; ++j) {
#pragma unroll
    for (int off = 1; off < 64; off <<= 1) {
      float om = __shfl_xor(mx[j], off, 64);
      float os = __shfl_xor(sm[j], off, 64);
      float ow = __shfl_xor(wc[j], off, 64);
      float nm = fmaxf(mx[j], om);
      float r1 = fexp2(mx[j]-nm);
      float r2 = fexp2(om-nm);
      sm[j] = sm[j]*r1 + os*r2;
      wc[j] = wc[j]*r1 + ow*r2;
      mx[j] = nm;
    }
  }
  if (lane == 0) {
#pragma unroll
    for (int j = 0; j < 8; ++j) {
      dout[b*N + r0 + j] = sqrtf(wc[j] / sm[j]);
    }
  }
}

__global__ __launch_bounds__(256) void emd_final2(const float* __restrict__ x1, const float* __restrict__ y1,
                                                  const float* __restrict__ g1, float* __restrict__ d1,
                                                  const float* __restrict__ x2, const float* __restrict__ y2,
                                                  const float* __restrict__ g2, float* __restrict__ d2,
                                                  const int* __restrict__ itersPtr) {
  const int use_g = (*itersPtr > 0) ? 1 : 0;
  __shared__ float tyx[EMD_TM], tyy[EMD_TM], tyz[EMD_TM], tg[EMD_TM];
  const int b = blockIdx.y;
  const int bx = blockIdx.x;
  if (bx < 32) {
    emd_final_body(x1, y1, g1, d1, 1024, use_g, b, bx, tyx, tyy, tyz, tg);
  } else {
    emd_final_body(x2, y2, g2, d2, 4096, use_g, b, bx-32, tyx, tyy, tyz, tg);
  }
}

// ---------------- merged chamfer mins: 304 blocks decoded into 4 regions ----------------
__global__ __launch_bounds__(256) void cham_all(const float* __restrict__ coarse,
                                                const float* __restrict__ fine,
                                                const float* __restrict__ gt,
                                                unsigned* __restrict__ A, unsigned* __restrict__ B,
                                                unsigned* __restrict__ C, unsigned* __restrict__ D) {
  __shared__ float tx[1024], ty[1024], tz[1024];
  const int id = blockIdx.x;
  const float* q; const float* tp; int nq, nt, chunk; unsigned* om; int qx, cy, b;
  if (id < 32)       { int r = id;       b = r>>4; qx = r&15;      cy = 0;    q = gt;     nq = 4096; tp = coarse; nt = 512;  chunk = 512;  om = A; }
  else if (id < 48)  { int r = id-32;    b = r>>3; qx = (r>>2)&1;  cy = r&3;  q = coarse; nq = 512;  tp = gt;     nt = 4096; chunk = 1024; om = B; }
  else if (id < 176) { int r = id-48;    b = r>>6; qx = (r>>2)&15; cy = r&3;  q = gt;     nq = 4096; tp = fine;   nt = 4096; chunk = 1024; om = C; }
  else               { int r = id-176;   b = r>>6; qx = (r>>2)&15; cy = r&3;  q = fine;   nq = 4096; tp = gt;     nt = 4096; chunk = 1024; om = D; }
  const int qi = qx*256 + threadIdx.x;
  const int cb = cy * chunk;
  for (int i = threadIdx.x; i < chunk; i += 256) {
    const float* pp = tp + (size_t)(b*nt + cb + i)*3;
    tx[i] = pp[0]; ty[i] = pp[1]; tz[i] = pp[2];
  }
  __syncthreads();
  const float* qp = q + (size_t)(b*nq + qi)*3;
  float qxv = qp[0], qyv = qp[1], qzv = qp[2];
  float m = 3.4e38f;
  for (int i = 0; i < chunk; ++i) {
    float dx = qxv-tx[i], dy = qyv-ty[i], dz = qzv-tz[i];
    float d = dx*dx + dy*dy + dz*dz;
    m = fminf(m, d);
  }
  atomicMin(&om[b*nq + qi], __float_as_uint(m));  // nonneg floats: uint order == float order
}

__device__ __forceinline__ float blk_sum(float v, float* lds) {
#pragma unroll
  for (int off = 32; off >= 1; off >>= 1) v += __shfl_xor(v, off, 64);
  int lane = threadIdx.x & 63, wv = threadIdx.x >> 6;
  __syncthreads();
  if (lane == 0) lds[wv] = v;
  __syncthreads();
  return lds[0]+lds[1]+lds[2]+lds[3];
}

// ---------------- finalize: emd means + chamfer reductions, one launch ----------------
__global__ __launch_bounds__(256) void finalize(const unsigned* __restrict__ A,
                                                const unsigned* __restrict__ B,
                                                const unsigned* __restrict__ C,
                                                const unsigned* __restrict__ D,
                                                const float* __restrict__ dv1,
                                                const float* __restrict__ dv2,
                                                float* __restrict__ out) {
  __shared__ float lds[4];
  int b = blockIdx.x;
  float e1 = 0, e2 = 0;
  for (int i = threadIdx.x; i < 1024; i += 256) e1 += dv1[b*1024+i];
  e1 = blk_sum(e1, lds);
  for (int i = threadIdx.x; i < 4096; i += 256) e2 += dv2[b*4096+i];
  e2 = blk_sum(e2, lds);
  float rA=0, sA=0, rB=0, sB=0, rC=0, sC=0, rD=0, sD=0;
  for (int i = threadIdx.x; i < 4096; i += 256) { float v = __uint_as_float(A[b*4096+i]); rA += v; sA += sqrtf(v); }
  rA = blk_sum(rA, lds); sA = blk_sum(sA, lds);
  for (int i = threadIdx.x; i < 512;  i += 256) { float v = __uint_as_float(B[b*512+i]);  rB += v; sB += sqrtf(v); }
  rB = blk_sum(rB, lds); sB = blk_sum(sB, lds);
  for (int i = threadIdx.x; i < 4096; i += 256) { float v = __uint_as_float(C[b*4096+i]); rC += v; sC += sqrtf(v); }
  rC = blk_sum(rC, lds); sC = blk_sum(sC, lds);
  for (int i = threadIdx.x; i < 4096; i += 256) { float v = __uint_as_float(D[b*4096+i]); rD += v; sD += sqrtf(v); }
  rD = blk_sum(rD, lds); sD = blk_sum(sD, lds);
  if (threadIdx.x == 0) {
    out[27648 + b] = e1 / 1024.0f;                    // emd1
    out[27650 + b] = e2 / 4096.0f;                    // emd2
    out[27652 + b] = 0.5f*(sA/4096.0f + sB/512.0f);   // cd1_p
    out[27654 + b] = 0.5f*(sC/4096.0f + sD/4096.0f);  // cd2_p
    out[27656 + b] = rA/4096.0f + rB/512.0f;          // cd1_t
    out[27658 + b] = rC/4096.0f + rD/4096.0f;         // cd2_t
  }
}

extern "C" void kernel_launch(void* const* d_in, const int* in_sizes, int n_in,
                              void* d_out, int out_size, void* d_ws, size_t ws_size,
                              hipStream_t stream) {
  (void)in_sizes; (void)n_in; (void)out_size; (void)ws_size;
  const float* coarse = (const float*)d_in[0];
  const float* fine   = (const float*)d_in[1];
  const float* gt     = (const float*)d_in[2];
  const int*   iters  = (const int*)d_in[3];
  float* out = (float*)d_out;
  float* ws  = (float*)d_ws;

  float* chamA = ws + 0;        // 2*4096  gt->coarse
  float* chamB = ws + 8192;     // 2*512   coarse->gt
  float* chamC = ws + 9216;     // 2*4096  gt->fine
  float* chamD = ws + 17408;    // 2*4096  fine->gt
  float* f1    = ws + 25600;    // 2*1024
  float* g1    = ws + 27648;    // 2*1024
  float* dv1   = ws + 29696;    // 2*1024
  float* f2    = ws + 31744;    // 2*4096
  float* g2    = ws + 39936;    // 2*4096
  float* dv2   = ws + 48128;    // 2*4096
  float* gtfps = ws + 56320;    // 2*1024*3
  float* xtile = ws + 62464;    // 2*1024*3

  hipMemsetAsync(ws, 0x7f, 25600*sizeof(float), stream);  // chamfer mins -> 3.39e38
  hipMemcpyAsync(out,        coarse, 3072*sizeof(float),  hipMemcpyDeviceToDevice, stream);
  hipMemcpyAsync(out + 3072, fine,   24576*sizeof(float), hipMemcpyDeviceToDevice, stream);

  prep_xtile<<<24, 256, 0, stream>>>(coarse, xtile);
  fps_kernel<<<2, 512, 0, stream>>>(gt, gtfps);

  // merged Sinkhorn: problem1 = (xtile, gtfps, N=1024), problem2 = (fine, gt, N=4096)
  for (int k = 0; k < 4; ++k) {
    // f-pass: rows = x side, vin = g
    emd_pass2<<<dim3(160,2), 256, 0, stream>>>(xtile, gtfps, g1, f1,
                                               fine,  gt,    g2, f2,
                                               k > 0 ? 1 : 0, k, iters);
    // g-pass: rows = y side, vin = f
    emd_pass2<<<dim3(160,2), 256, 0, stream>>>(gtfps, xtile, f1, g1,
                                               gt,    fine,  f2, g2,
                                               1, k, iters);
  }
  emd_final2<<<dim3(160,2), 256, 0, stream>>>(xtile, gtfps, g1, dv1,
                                              fine,  gt,    g2, dv2, iters);

  cham_all<<<304, 256, 0, stream>>>(coarse, fine, gt,
                                    (unsigned*)chamA, (unsigned*)chamB,
                                    (unsigned*)chamC, (unsigned*)chamD);
  finalize<<<2, 256, 0, stream>>>((unsigned*)chamA, (unsigned*)chamB,
                                  (unsigned*)chamC, (unsigned*)chamD,
                                  dv1, dv2, out);
}

// Round 5
// 1276.981 us; speedup vs baseline: 1.6430x; 1.4036x over previous
//
#include <hip/hip_runtime.h>
#include <math.h>

static constexpr float EPS_SK = 0.02f;
static constexpr float LOG2E  = 1.4426950408889634f;
static constexpr float LN2F   = 0.6931471805599453f;
#define LOGN1 6.931471805599453f   /* log 1024 */
#define LOGN2 8.317766166719343f   /* log 4096 */

__device__ __forceinline__ float fexp2(float x){ return __builtin_amdgcn_exp2f(x); }
__device__ __forceinline__ float flog2(float x){ return __builtin_amdgcn_logf(x); }

// ======================= LDS union for the mega kernel =======================
union MegaLds {
  struct {
    float4 sp[4096];                 // 64 KB points
    float4 ob[1024];                 // 16 KB selected-point buffer
    unsigned long long sl[2][8];     // parity-double-buffered wave winners
  } fps;
  struct { float x[1024], y[1024], z[1024]; } ch;
};

// DPP-based argmax step: pure VALU cross-lane. max by (value, then smaller idx).
template<int CTRL>
__device__ __forceinline__ void dpp_amax(float& bv, int& bi) {
  float ov = __int_as_float(__builtin_amdgcn_update_dpp(
      __float_as_int(bv), __float_as_int(bv), CTRL, 0xF, 0xF, false));
  int oi = __builtin_amdgcn_update_dpp(bi, bi, CTRL, 0xF, 0xF, false);
  if (ov > bv || (ov == bv && oi < bi)) { bv = ov; bi = oi; }
}

// ---------------- FPS body: 512 threads (8 waves), 8 pts/lane ----------------
__device__ __forceinline__ void fps_body(MegaLds& L, const float* __restrict__ gt,
                                         float* __restrict__ gt_fps, int b) {
  const int t = threadIdx.x;
  const int lane = t & 63;
  const int wv   = t >> 6;
  const float* P = gt + (size_t)b*4096*3;
  for (int i = t; i < 4096; i += 512)
    L.fps.sp[i] = make_float4(P[i*3+0], P[i*3+1], P[i*3+2], 0.0f);
  __syncthreads();
  float px[8], py[8], pz[8], dst[8];
#pragma unroll
  for (int j = 0; j < 8; ++j) {
    float4 q = L.fps.sp[t*8 + j];            // idx = t*8+j (contiguous, j-ascending)
    px[j] = q.x; py[j] = q.y; pz[j] = q.z;
    dst[j] = 1e10f;                          // matches reference init
  }
  float cx, cy, cz;
  { float4 q = L.fps.sp[0]; cx = q.x; cy = q.y; cz = q.z;
    if (t == 0) L.fps.ob[0] = q; }
  for (int s = 1; s < 1024; ++s) {
    float bv = -1.0f; int bj = 0;
    {
#pragma clang fp contract(off)
#pragma unroll
      for (int j = 0; j < 8; ++j) {
        float dx = px[j]-cx, dy = py[j]-cy, dz = pz[j]-cz;
        float d  = dx*dx + dy*dy + dz*dz;
        float nd = fminf(dst[j], d);
        dst[j] = nd;
        if (nd > bv) { bv = nd; bj = j; }    // strict >, j ascending: first-max kept
      }
    }
    int bi = t*8 + bj;
    dpp_amax<0x111>(bv, bi);  // row_shr:1
    dpp_amax<0x112>(bv, bi);  // row_shr:2
    dpp_amax<0x114>(bv, bi);  // row_shr:4
    dpp_amax<0x118>(bv, bi);  // row_shr:8
    dpp_amax<0x142>(bv, bi);  // row_bcast15
    dpp_amax<0x143>(bv, bi);  // row_bcast31
    const int pb = s & 1;
    if (lane == 63)
      L.fps.sl[pb][wv] = (((unsigned long long)__float_as_uint(bv)) << 32)
                         | (unsigned)(~bi);  // bigger packed = bigger val or smaller idx
    __syncthreads();
    ulonglong2 a0 = *(const ulonglong2*)&L.fps.sl[pb][0];
    ulonglong2 a1 = *(const ulonglong2*)&L.fps.sl[pb][2];
    ulonglong2 a2 = *(const ulonglong2*)&L.fps.sl[pb][4];
    ulonglong2 a3 = *(const ulonglong2*)&L.fps.sl[pb][6];
    unsigned long long bp = a0.x;
    if (a0.y > bp) bp = a0.y;
    if (a1.x > bp) bp = a1.x;
    if (a1.y > bp) bp = a1.y;
    if (a2.x > bp) bp = a2.x;
    if (a2.y > bp) bp = a2.y;
    if (a3.x > bp) bp = a3.x;
    if (a3.y > bp) bp = a3.y;
    int idxw = (int)(~(unsigned)bp);
    float4 c4 = L.fps.sp[idxw];
    cx = c4.x; cy = c4.y; cz = c4.z;
    if (t == 0) L.fps.ob[s] = c4;            // LDS write only — no vmcnt at barrier
  }
  __syncthreads();
  for (int i = t; i < 1024; i += 512) {      // one bulk global store at the end
    float4 f4 = L.fps.ob[i];
    float* o = gt_fps + (size_t)(b*1024 + i)*3;
    o[0] = f4.x; o[1] = f4.y; o[2] = f4.z;
  }
}

// ============ mega kernel: fps(2) + init/copies(66) + chamfer(50) ============
__global__ __launch_bounds__(512) void mega(const float* __restrict__ coarse,
                                            const float* __restrict__ fine,
                                            const float* __restrict__ gt,
                                            float* __restrict__ gtfps,
                                            float* __restrict__ xtile,
                                            float* __restrict__ chamA, float* __restrict__ chamB,
                                            float* __restrict__ chamC, float* __restrict__ chamD,
                                            float* __restrict__ out) {
  __shared__ MegaLds L;
  const int blk = blockIdx.x;
  const int t = threadIdx.x;
  if (blk < 2) { fps_body(L, gt, gtfps, blk); return; }
  if (blk < 68) {                            // init: out copies + xtile
    int i = (blk-2)*512 + t;
    if (i < 3072)       out[i] = coarse[i];
    else if (i < 27648) out[i] = fine[i-3072];
    else {
      int j = i - 27648;                     // < 6144
      int bb = j / 3072; int r = (j % 3072) / 3; int c = j % 3;
      xtile[j] = coarse[(size_t)(bb*512 + (r & 511))*3 + c];
    }
    return;
  }
  // chamfer: per-query exact min, tiles looped inside the block (no atomics)
  int cid = blk - 68;
  const float *q, *tp; float* om; int nq, nt, b, qx;
  if (cid < 16)      { b = cid>>3;        qx = cid&7; q = gt;     nq = 4096; tp = coarse; nt = 512;  om = chamA; }
  else if (cid < 18) { b = cid-16;        qx = 0;     q = coarse; nq = 512;  tp = gt;     nt = 4096; om = chamB; }
  else if (cid < 34) { int r = cid-18; b = r>>3; qx = r&7; q = gt;   nq = 4096; tp = fine; nt = 4096; om = chamC; }
  else               { int r = cid-34; b = r>>3; qx = r&7; q = fine; nq = 4096; tp = gt;   nt = 4096; om = chamD; }
  const int qi = qx*512 + t;
  const float* qp = q + (size_t)(b*nq + qi)*3;
  float qxv = qp[0], qyv = qp[1], qzv = qp[2];
  float m = 3.4e38f;
  for (int tt0 = 0; tt0 < nt; tt0 += 1024) {
    int chunk = min(1024, nt - tt0);
    __syncthreads();
    for (int i = t; i < chunk; i += 512) {
      const float* pp = tp + (size_t)(b*nt + tt0 + i)*3;
      L.ch.x[i] = pp[0]; L.ch.y[i] = pp[1]; L.ch.z[i] = pp[2];
    }
    __syncthreads();
    for (int i = 0; i < chunk; ++i) {
      float dx = qxv-L.ch.x[i], dy = qyv-L.ch.y[i], dz = qzv-L.ch.z[i];
      float d = dx*dx + dy*dy + dz*dz;
      m = fminf(m, d);
    }
  }
  om[b*nq + qi] = m;
}

// ======================= EMD bodies (R2-proven, plain mem ops) ===============
__device__ __forceinline__ void emd_pass_body(const float* __restrict__ xpts,
                                              const float* __restrict__ ypts,
                                              const float* __restrict__ vin,
                                              float* __restrict__ vout,
                                              int N, float logN, int use_vin,
                                              int b, int bx,
                                              float* tyx, float* tyy, float* tyz, float* tg) {
  const int t = threadIdx.x;
  const int lane = t & 63;
  const int wv   = t >> 6;
  const int r0 = bx*32 + wv*8;
  float px[8], py[8], pz[8], mx[8], sm[8];
#pragma unroll
  for (int j = 0; j < 8; ++j) {
    const float* xp = xpts + (size_t)(b*N + r0 + j)*3;
    px[j] = xp[0]; py[j] = xp[1]; pz[j] = xp[2];
    mx[j] = -3.4e38f; sm[j] = 0.0f;
  }
  const float S = LOG2E / EPS_SK;
  const int ntiles = N / 1024;
  for (int tt = 0; tt < ntiles; ++tt) {
    const int base = tt*1024;
    __syncthreads();
    for (int i = t; i < 1024; i += 256) {
      const float* yp = ypts + (size_t)(b*N + base + i)*3;
      tyx[i] = yp[0]; tyy[i] = yp[1]; tyz[i] = yp[2];
      tg[i]  = use_vin ? vin[b*N + base + i] : 0.0f;
    }
    __syncthreads();
    for (int mi = lane; mi < 1024; mi += 64) {
      float yx = tyx[mi], yy = tyy[mi], yz = tyz[mi], g = tg[mi];
#pragma unroll
      for (int j = 0; j < 8; ++j) {
        float dx = px[j]-yx, dy = py[j]-yy, dz = pz[j]-yz;
        float d  = dx*dx + dy*dy + dz*dz;
        float tv = (g - d) * S;
        float nm = fmaxf(mx[j], tv);
        sm[j] = sm[j]*fexp2(mx[j]-nm) + fexp2(tv-nm);
        mx[j] = nm;
      }
    }
  }
#pragma unroll
  for (int j = 0; j < 8; ++j) {
#pragma unroll
    for (int off = 1; off < 64; off <<= 1) {
      float om = __shfl_xor(mx[j], off, 64);
      float os = __shfl_xor(sm[j], off, 64);
      float nm = fmaxf(mx[j], om);
      sm[j] = sm[j]*fexp2(mx[j]-nm) + os*fexp2(om-nm);
      mx[j] = nm;
    }
  }
  if (lane == 0) {
#pragma unroll
    for (int j = 0; j < 8; ++j) {
      float lse = (mx[j] + flog2(sm[j])) * LN2F;
      vout[b*N + r0 + j] = -EPS_SK * (lse + logN);
    }
  }
}

__global__ __launch_bounds__(256) void emd_pass2(const float* __restrict__ x1, const float* __restrict__ y1,
                                                 const float* __restrict__ v1in, float* __restrict__ v1out,
                                                 const float* __restrict__ x2, const float* __restrict__ y2,
                                                 const float* __restrict__ v2in, float* __restrict__ v2out,
                                                 int use_vin, int k, const int* __restrict__ itersPtr) {
  if (k >= *itersPtr) return;
  __shared__ float tyx[1024], tyy[1024], tyz[1024], tg[1024];
  const int b = blockIdx.y;
  const int bx = blockIdx.x;
  if (bx < 32) {
    emd_pass_body(x1, y1, v1in, v1out, 1024, LOGN1, use_vin, b, bx, tyx, tyy, tyz, tg);
  } else {
    emd_pass_body(x2, y2, v2in, v2out, 4096, LOGN2, use_vin, b, bx-32, tyx, tyy, tyz, tg);
  }
}

__device__ __forceinline__ void emd_final_body(const float* __restrict__ xpts,
                                               const float* __restrict__ ypts,
                                               const float* __restrict__ gin,
                                               float* __restrict__ dout,
                                               int N, int use_g, int b, int bx,
                                               float* tyx, float* tyy, float* tyz, float* tg) {
  const int t = threadIdx.x;
  const int lane = t & 63;
  const int wv   = t >> 6;
  const int r0 = bx*32 + wv*8;
  float px[8], py[8], pz[8], mx[8], sm[8], wc[8];
#pragma unroll
  for (int j = 0; j < 8; ++j) {
    const float* xp = xpts + (size_t)(b*N + r0 + j)*3;
    px[j] = xp[0]; py[j] = xp[1]; pz[j] = xp[2];
    mx[j] = -3.4e38f; sm[j] = 0.0f; wc[j] = 0.0f;
  }
  const float S = LOG2E / EPS_SK;
  const int ntiles = N / 1024;
  for (int tt = 0; tt < ntiles; ++tt) {
    const int base = tt*1024;
    __syncthreads();
    for (int i = t; i < 1024; i += 256) {
      const float* yp = ypts + (size_t)(b*N + base + i)*3;
      tyx[i] = yp[0]; tyy[i] = yp[1]; tyz[i] = yp[2];
      tg[i]  = use_g ? gin[b*N + base + i] : 0.0f;
    }
    __syncthreads();
    for (int mi = lane; mi < 1024; mi += 64) {
      float yx = tyx[mi], yy = tyy[mi], yz = tyz[mi], g = tg[mi];
#pragma unroll
      for (int j = 0; j < 8; ++j) {
        float dx = px[j]-yx, dy = py[j]-yy, dz = pz[j]-yz;
        float d  = dx*dx + dy*dy + dz*dz;
        float tv = (g - d) * S;
        float nm = fmaxf(mx[j], tv);
        float r  = fexp2(mx[j]-nm);
        float e  = fexp2(tv-nm);
        sm[j] = sm[j]*r + e;
        wc[j] = wc[j]*r + e*d;
        mx[j] = nm;
      }
    }
  }
#pragma unroll
  for (int j = 0; j < 8; ++j) {
#pragma unroll
    for (int off = 1; off < 64; off <<= 1) {
      float om = __shfl_xor(mx[j], off, 64);
      float os = __shfl_xor(sm[j], off, 64);
      float ow = __shfl_xor(wc[j], off, 64);
      float nm = fmaxf(mx[j], om);
      float r1 = fexp2(mx[j]-nm);
      float r2 = fexp2(om-nm);
      sm[j] = sm[j]*r1 + os*r2;
      wc[j] = wc[j]*r1 + ow*r2;
      mx[j] = nm;
    }
  }
  if (lane == 0) {
#pragma unroll
    for (int j = 0; j < 8; ++j)
      dout[b*N + r0 + j] = sqrtf(wc[j] / sm[j]);
  }
}

__global__ __launch_bounds__(256) void emd_final2(const float* __restrict__ x1, const float* __restrict__ y1,
                                                  const float* __restrict__ g1, float* __restrict__ d1,
                                                  const float* __restrict__ x2, const float* __restrict__ y2,
                                                  const float* __restrict__ g2, float* __restrict__ d2,
                                                  const int* __restrict__ itersPtr) {
  const int use_g = (*itersPtr > 0) ? 1 : 0;
  __shared__ float tyx[1024], tyy[1024], tyz[1024], tg[1024];
  const int b = blockIdx.y;
  const int bx = blockIdx.x;
  if (bx < 32) {
    emd_final_body(x1, y1, g1, d1, 1024, use_g, b, bx, tyx, tyy, tyz, tg);
  } else {
    emd_final_body(x2, y2, g2, d2, 4096, use_g, b, bx-32, tyx, tyy, tyz, tg);
  }
}

__device__ __forceinline__ float blk_sum(float v, float* lds) {
#pragma unroll
  for (int off = 32; off >= 1; off >>= 1) v += __shfl_xor(v, off, 64);
  int lane = threadIdx.x & 63, wv = threadIdx.x >> 6;
  __syncthreads();
  if (lane == 0) lds[wv] = v;
  __syncthreads();
  return lds[0]+lds[1]+lds[2]+lds[3];
}

// ---------------- finalize: emd means + chamfer reductions, one launch -------
__global__ __launch_bounds__(256) void finalize(const float* __restrict__ A,
                                                const float* __restrict__ B,
                                                const float* __restrict__ C,
                                                const float* __restrict__ D,
                                                const float* __restrict__ dv1,
                                                const float* __restrict__ dv2,
                                                float* __restrict__ out) {
  __shared__ float lds[4];
  int b = blockIdx.x;
  float e1 = 0, e2 = 0;
  for (int i = threadIdx.x; i < 1024; i += 256) e1 += dv1[b*1024+i];
  e1 = blk_sum(e1, lds);
  for (int i = threadIdx.x; i < 4096; i += 256) e2 += dv2[b*4096+i];
  e2 = blk_sum(e2, lds);
  float rA=0, sA=0, rB=0, sB=0, rC=0, sC=0, rD=0, sD=0;
  for (int i = threadIdx.x; i < 4096; i += 256) { float v = A[b*4096+i]; rA += v; sA += sqrtf(v); }
  rA = blk_sum(rA, lds); sA = blk_sum(sA, lds);
  for (int i = threadIdx.x; i < 512;  i += 256) { float v = B[b*512+i];  rB += v; sB += sqrtf(v); }
  rB = blk_sum(rB, lds); sB = blk_sum(sB, lds);
  for (int i = threadIdx.x; i < 4096; i += 256) { float v = C[b*4096+i]; rC += v; sC += sqrtf(v); }
  rC = blk_sum(rC, lds); sC = blk_sum(sC, lds);
  for (int i = threadIdx.x; i < 4096; i += 256) { float v = D[b*4096+i]; rD += v; sD += sqrtf(v); }
  rD = blk_sum(rD, lds); sD = blk_sum(sD, lds);
  if (threadIdx.x == 0) {
    out[27648 + b] = e1 / 1024.0f;                    // emd1
    out[27650 + b] = e2 / 4096.0f;                    // emd2
    out[27652 + b] = 0.5f*(sA/4096.0f + sB/512.0f);   // cd1_p
    out[27654 + b] = 0.5f*(sC/4096.0f + sD/4096.0f);  // cd2_p
    out[27656 + b] = rA/4096.0f + rB/512.0f;          // cd1_t
    out[27658 + b] = rC/4096.0f + rD/4096.0f;         // cd2_t
  }
}

extern "C" void kernel_launch(void* const* d_in, const int* in_sizes, int n_in,
                              void* d_out, int out_size, void* d_ws, size_t ws_size,
                              hipStream_t stream) {
  (void)in_sizes; (void)n_in; (void)out_size; (void)ws_size;
  const float* coarse = (const float*)d_in[0];
  const float* fine   = (const float*)d_in[1];
  const float* gt     = (const float*)d_in[2];
  const int*   iters  = (const int*)d_in[3];
  float* out = (float*)d_out;
  float* ws  = (float*)d_ws;

  float* chamA = ws + 0;        // 2*4096
  float* chamB = ws + 8192;     // 2*512
  float* chamC = ws + 9216;     // 2*4096
  float* chamD = ws + 17408;    // 2*4096
  float* f1    = ws + 25600;    // 2*1024
  float* g1    = ws + 27648;    // 2*1024
  float* dv1   = ws + 29696;    // 2*1024
  float* f2    = ws + 31744;    // 2*4096
  float* g2    = ws + 39936;    // 2*4096
  float* dv2   = ws + 48128;    // 2*4096
  float* gtfps = ws + 56320;    // 2*1024*3
  float* xtile = ws + 62464;    // 2*1024*3

  mega<<<118, 512, 0, stream>>>(coarse, fine, gt, gtfps, xtile,
                                chamA, chamB, chamC, chamD, out);

  for (int k = 0; k < 4; ++k) {
    emd_pass2<<<dim3(160,2), 256, 0, stream>>>(xtile, gtfps, g1, f1,
                                               fine,  gt,    g2, f2,
                                               k > 0 ? 1 : 0, k, iters);
    emd_pass2<<<dim3(160,2), 256, 0, stream>>>(gtfps, xtile, f1, g1,
                                               gt,    fine,  f2, g2,
                                               1, k, iters);
  }
  emd_final2<<<dim3(160,2), 256, 0, stream>>>(xtile, gtfps, g1, dv1,
                                              fine,  gt,    g2, dv2, iters);
  finalize<<<2, 256, 0, stream>>>(chamA, chamB, chamC, chamD, dv1, dv2, out);
}

// Round 6
// 1086.831 us; speedup vs baseline: 1.9305x; 1.1750x over previous
//
#include <hip/hip_runtime.h>
#include <math.h>

static constexpr float EPS_SK = 0.02f;
static constexpr float LOG2E  = 1.4426950408889634f;
static constexpr float LN2F   = 0.6931471805599453f;
#define LOGN1 6.931471805599453f   /* log 1024 */
#define LOGN2 8.317766166719343f   /* log 4096 */

__device__ __forceinline__ float fexp2(float x){ return __builtin_amdgcn_exp2f(x); }
__device__ __forceinline__ float flog2(float x){ return __builtin_amdgcn_logf(x); }

// ======================= LDS union (78 KB -> 1 block/CU, 252 blocks co-resident) ====
union Lds {
  struct {
    float4 sp[4096];                 // 64 KB points
    float  obx[1024], oby[1024], obz[1024];  // 12 KB selected-point buffer
    unsigned long long sl[2][8];     // parity-double-buffered wave winners
  } fps;
  struct { float tyx[1024], tyy[1024], tyz[1024], tg[1024]; } emd;
  struct { float x[1024], y[1024], z[1024]; } ch;
};

// ---------------- sync primitives (validated by R3's emd1 path) ----------------
__device__ __forceinline__ void gbar(unsigned* cnt, unsigned* gen, unsigned nblk) {
  __threadfence();
  __syncthreads();
  if (threadIdx.x == 0) {
    unsigned g = __hip_atomic_load(gen, __ATOMIC_ACQUIRE, __HIP_MEMORY_SCOPE_AGENT);
    if (__hip_atomic_fetch_add(cnt, 1u, __ATOMIC_ACQ_REL, __HIP_MEMORY_SCOPE_AGENT) == nblk - 1u) {
      __hip_atomic_store(cnt, 0u, __ATOMIC_RELAXED, __HIP_MEMORY_SCOPE_AGENT);
      __hip_atomic_fetch_add(gen, 1u, __ATOMIC_ACQ_REL, __HIP_MEMORY_SCOPE_AGENT);
    } else {
      while (__hip_atomic_load(gen, __ATOMIC_ACQUIRE, __HIP_MEMORY_SCOPE_AGENT) == g)
        __builtin_amdgcn_s_sleep(8);
    }
  }
  __syncthreads();
  __threadfence();
}

__device__ __forceinline__ void signal_done(unsigned* f) {
  __threadfence();
  __syncthreads();
  if (threadIdx.x == 0)
    __hip_atomic_fetch_add(f, 1u, __ATOMIC_RELEASE, __HIP_MEMORY_SCOPE_AGENT);
}

__device__ __forceinline__ void waitcnt_ge(unsigned* f, unsigned target) {
  if (threadIdx.x == 0)
    while (__hip_atomic_load(f, __ATOMIC_ACQUIRE, __HIP_MEMORY_SCOPE_AGENT) < target)
      __builtin_amdgcn_s_sleep(16);
  __syncthreads();
  __threadfence();
}

// DPP-based argmax step: pure VALU cross-lane. max by (value, then smaller idx).
template<int CTRL>
__device__ __forceinline__ void dpp_amax(float& bv, int& bi) {
  float ov = __int_as_float(__builtin_amdgcn_update_dpp(
      __float_as_int(bv), __float_as_int(bv), CTRL, 0xF, 0xF, false));
  int oi = __builtin_amdgcn_update_dpp(bi, bi, CTRL, 0xF, 0xF, false);
  if (ov > bv || (ov == bv && oi < bi)) { bv = ov; bi = oi; }
}

// ---------------- FPS body: 512 threads (8 waves), 8 pts/lane (R5-proven) ------
__device__ __forceinline__ void fps_body(Lds& L, const float* __restrict__ gt,
                                         float* __restrict__ gt_fps, int b) {
  const int t = threadIdx.x;
  const int lane = t & 63;
  const int wv   = t >> 6;
  const float* P = gt + (size_t)b*4096*3;
  for (int i = t; i < 4096; i += 512)
    L.fps.sp[i] = make_float4(P[i*3+0], P[i*3+1], P[i*3+2], 0.0f);
  __syncthreads();
  float px[8], py[8], pz[8], dst[8];
#pragma unroll
  for (int j = 0; j < 8; ++j) {
    float4 q = L.fps.sp[t*8 + j];            // idx = t*8+j (contiguous, j-ascending)
    px[j] = q.x; py[j] = q.y; pz[j] = q.z;
    dst[j] = 1e10f;                          // matches reference init
  }
  float cx, cy, cz;
  { float4 q = L.fps.sp[0]; cx = q.x; cy = q.y; cz = q.z;
    if (t == 0) { L.fps.obx[0] = q.x; L.fps.oby[0] = q.y; L.fps.obz[0] = q.z; } }
  for (int s = 1; s < 1024; ++s) {
    float bv = -1.0f; int bj = 0;
    {
#pragma clang fp contract(off)
#pragma unroll
      for (int j = 0; j < 8; ++j) {
        float dx = px[j]-cx, dy = py[j]-cy, dz = pz[j]-cz;
        float d  = dx*dx + dy*dy + dz*dz;
        float nd = fminf(dst[j], d);
        dst[j] = nd;
        if (nd > bv) { bv = nd; bj = j; }    // strict >, j ascending: first-max kept
      }
    }
    int bi = t*8 + bj;
    dpp_amax<0x111>(bv, bi);  // row_shr:1
    dpp_amax<0x112>(bv, bi);  // row_shr:2
    dpp_amax<0x114>(bv, bi);  // row_shr:4
    dpp_amax<0x118>(bv, bi);  // row_shr:8
    dpp_amax<0x142>(bv, bi);  // row_bcast15
    dpp_amax<0x143>(bv, bi);  // row_bcast31
    const int pb = s & 1;
    if (lane == 63)
      L.fps.sl[pb][wv] = (((unsigned long long)__float_as_uint(bv)) << 32)
                         | (unsigned)(~bi);  // bigger packed = bigger val or smaller idx
    __syncthreads();
    ulonglong2 a0 = *(const ulonglong2*)&L.fps.sl[pb][0];
    ulonglong2 a1 = *(const ulonglong2*)&L.fps.sl[pb][2];
    ulonglong2 a2 = *(const ulonglong2*)&L.fps.sl[pb][4];
    ulonglong2 a3 = *(const ulonglong2*)&L.fps.sl[pb][6];
    unsigned long long bp = a0.x;
    if (a0.y > bp) bp = a0.y;
    if (a1.x > bp) bp = a1.x;
    if (a1.y > bp) bp = a1.y;
    if (a2.x > bp) bp = a2.x;
    if (a2.y > bp) bp = a2.y;
    if (a3.x > bp) bp = a3.x;
    if (a3.y > bp) bp = a3.y;
    int idxw = (int)(~(unsigned)bp);
    float4 c4 = L.fps.sp[idxw];
    cx = c4.x; cy = c4.y; cz = c4.z;
    if (t == 0) { L.fps.obx[s] = c4.x; L.fps.oby[s] = c4.y; L.fps.obz[s] = c4.z; }
  }
  __syncthreads();
  for (int i = t; i < 1024; i += 512) {      // one bulk global store at the end
    float* o = gt_fps + (size_t)(b*1024 + i)*3;
    o[0] = L.fps.obx[i]; o[1] = L.fps.oby[i]; o[2] = L.fps.obz[i];
  }
}

// ============== EMD bodies, 512 threads, 64 rows/block, masked row wrap ========
__device__ __forceinline__ void emd_pass_512(
    const float* __restrict__ xb, int xm,
    const float* __restrict__ yb, int ym,
    const float* __restrict__ vinb, float* __restrict__ voutb,
    int N, float logN, int use_vin, int r0b,
    float* tyx, float* tyy, float* tyz, float* tg)
{
  const int t = threadIdx.x;
  const int lane = t & 63;
  const int wv   = t >> 6;
  const int r0 = r0b + wv*8;
  float px[8], py[8], pz[8], mx[8], sm[8];
#pragma unroll
  for (int j = 0; j < 8; ++j) {
    const int row = (r0 + j) & xm;
    const float* xp = xb + (size_t)row*3;
    px[j] = xp[0]; py[j] = xp[1]; pz[j] = xp[2];
    mx[j] = -3.4e38f; sm[j] = 0.0f;
  }
  const float S = LOG2E / EPS_SK;
  const int ntiles = N >> 10;
  for (int tt = 0; tt < ntiles; ++tt) {
    const int base = tt << 10;
    __syncthreads();
    for (int i = t; i < 1024; i += 512) {
      const int row = (base + i) & ym;
      const float* yp = yb + (size_t)row*3;
      tyx[i] = yp[0]; tyy[i] = yp[1]; tyz[i] = yp[2];
      tg[i]  = use_vin ? vinb[base + i] : 0.0f;
    }
    __syncthreads();
    for (int mi = lane; mi < 1024; mi += 64) {
      float yx = tyx[mi], yy = tyy[mi], yz = tyz[mi], g = tg[mi];
#pragma unroll
      for (int j = 0; j < 8; ++j) {
        float dx = px[j]-yx, dy = py[j]-yy, dz = pz[j]-yz;
        float d  = dx*dx + dy*dy + dz*dz;
        float tv = (g - d) * S;          // (g - C)/eps in log2 domain
        float nm = fmaxf(mx[j], tv);
        sm[j] = sm[j]*fexp2(mx[j]-nm) + fexp2(tv-nm);
        mx[j] = nm;
      }
    }
  }
#pragma unroll
  for (int j = 0; j < 8; ++j) {
#pragma unroll
    for (int off = 1; off < 64; off <<= 1) {
      float om = __shfl_xor(mx[j], off, 64);
      float os = __shfl_xor(sm[j], off, 64);
      float nm = fmaxf(mx[j], om);
      sm[j] = sm[j]*fexp2(mx[j]-nm) + os*fexp2(om-nm);
      mx[j] = nm;
    }
  }
  if (lane == 0) {
#pragma unroll
    for (int j = 0; j < 8; ++j) {
      float lse = (mx[j] + flog2(sm[j])) * LN2F;   // natural-log LSE
      voutb[r0 + j] = -EPS_SK * (lse + logN);
    }
  }
}

__device__ __forceinline__ void emd_final_512(
    const float* __restrict__ xb, int xm,
    const float* __restrict__ yb, int ym,
    const float* __restrict__ ginb, float* __restrict__ doutb,
    int N, int use_g, int r0b,
    float* tyx, float* tyy, float* tyz, float* tg)
{
  const int t = threadIdx.x;
  const int lane = t & 63;
  const int wv   = t >> 6;
  const int r0 = r0b + wv*8;
  float px[8], py[8], pz[8], mx[8], sm[8], wc[8];
#pragma unroll
  for (int j = 0; j < 8; ++j) {
    const int row = (r0 + j) & xm;
    const float* xp = xb + (size_t)row*3;
    px[j] = xp[0]; py[j] = xp[1]; pz[j] = xp[2];
    mx[j] = -3.4e38f; sm[j] = 0.0f; wc[j] = 0.0f;
  }
  const float S = LOG2E / EPS_SK;
  const int ntiles = N >> 10;
  for (int tt = 0; tt < ntiles; ++tt) {
    const int base = tt << 10;
    __syncthreads();
    for (int i = t; i < 1024; i += 512) {
      const int row = (base + i) & ym;
      const float* yp = yb + (size_t)row*3;
      tyx[i] = yp[0]; tyy[i] = yp[1]; tyz[i] = yp[2];
      tg[i]  = use_g ? ginb[base + i] : 0.0f;
    }
    __syncthreads();
    for (int mi = lane; mi < 1024; mi += 64) {
      float yx = tyx[mi], yy = tyy[mi], yz = tyz[mi], g = tg[mi];
#pragma unroll
      for (int j = 0; j < 8; ++j) {
        float dx = px[j]-yx, dy = py[j]-yy, dz = pz[j]-yz;
        float d  = dx*dx + dy*dy + dz*dz;
        float tv = (g - d) * S;
        float nm = fmaxf(mx[j], tv);
        float r  = fexp2(mx[j]-nm);
        float e  = fexp2(tv-nm);
        sm[j] = sm[j]*r + e;
        wc[j] = wc[j]*r + e*d;
        mx[j] = nm;
      }
    }
  }
#pragma unroll
  for (int j = 0; j < 8; ++j) {
#pragma unroll
    for (int off = 1; off < 64; off <<= 1) {
      float om = __shfl_xor(mx[j], off, 64);
      float os = __shfl_xor(sm[j], off, 64);
      float ow = __shfl_xor(wc[j], off, 64);
      float nm = fmaxf(mx[j], om);
      float r1 = fexp2(mx[j]-nm);
      float r2 = fexp2(om-nm);
      sm[j] = sm[j]*r1 + os*r2;
      wc[j] = wc[j]*r1 + ow*r2;
      mx[j] = nm;
    }
  }
  if (lane == 0) {
#pragma unroll
    for (int j = 0; j < 8; ++j)
      doutb[r0 + j] = sqrtf(wc[j] / sm[j]);
  }
}

__device__ __forceinline__ float blk_sum512(float v, float* lds) {
#pragma unroll
  for (int off = 32; off >= 1; off >>= 1) v += __shfl_xor(v, off, 64);
  int lane = threadIdx.x & 63, wv = threadIdx.x >> 6;
  __syncthreads();
  if (lane == 0) lds[wv] = v;
  __syncthreads();
  return lds[0]+lds[1]+lds[2]+lds[3]+lds[4]+lds[5]+lds[6]+lds[7];
}

__device__ __forceinline__ void finalize_body(int b,
    const float* __restrict__ A, const float* __restrict__ B,
    const float* __restrict__ C, const float* __restrict__ D,
    const float* __restrict__ dv1, const float* __restrict__ dv2,
    float* __restrict__ out, float* lds) {
  const int t = threadIdx.x;
  float e1 = 0, e2 = 0;
  for (int i = t; i < 1024; i += 512) e1 += dv1[b*1024+i];
  e1 = blk_sum512(e1, lds);
  for (int i = t; i < 4096; i += 512) e2 += dv2[b*4096+i];
  e2 = blk_sum512(e2, lds);
  float rA=0, sA=0, rB=0, sB=0, rC=0, sC=0, rD=0, sD=0;
  for (int i = t; i < 4096; i += 512) { float v = A[b*4096+i]; rA += v; sA += sqrtf(v); }
  rA = blk_sum512(rA, lds); sA = blk_sum512(sA, lds);
  for (int i = t; i < 512;  i += 512) { float v = B[b*512+i];  rB += v; sB += sqrtf(v); }
  rB = blk_sum512(rB, lds); sB = blk_sum512(sB, lds);
  for (int i = t; i < 4096; i += 512) { float v = C[b*4096+i]; rC += v; sC += sqrtf(v); }
  rC = blk_sum512(rC, lds); sC = blk_sum512(sC, lds);
  for (int i = t; i < 4096; i += 512) { float v = D[b*4096+i]; rD += v; sD += sqrtf(v); }
  rD = blk_sum512(rD, lds); sD = blk_sum512(sD, lds);
  if (t == 0) {
    out[27648 + b] = e1 / 1024.0f;                    // emd1
    out[27650 + b] = e2 / 4096.0f;                    // emd2
    out[27652 + b] = 0.5f*(sA/4096.0f + sB/512.0f);   // cd1_p
    out[27654 + b] = 0.5f*(sC/4096.0f + sD/4096.0f);  // cd2_p
    out[27656 + b] = rA/4096.0f + rB/512.0f;          // cd1_t
    out[27658 + b] = rC/4096.0f + rD/4096.0f;         // cd2_t
  }
}

// ---- tiny init: zero the 8 sync words (replay-safe; ws is never re-poisoned) ----
__global__ void init_sync(unsigned* __restrict__ sync) {
  if (threadIdx.x < 8)
    __hip_atomic_store(&sync[threadIdx.x], 0u, __ATOMIC_RELAXED, __HIP_MEMORY_SCOPE_AGENT);
}

// ===================== the one big kernel: 252 blocks x 512 ====================
// blk 0-1: FPS  | 2-129: EMD2 persistent | 130-161: EMD1 persistent (+finalize)
// blk 162-211: chamfer | 212-251: output copies
__global__ __launch_bounds__(512) void everything(
    const float* __restrict__ coarse, const float* __restrict__ fine,
    const float* __restrict__ gt, const int* __restrict__ itersPtr,
    float* __restrict__ chamA, float* __restrict__ chamB,
    float* __restrict__ chamC, float* __restrict__ chamD,
    float* __restrict__ f1, float* __restrict__ g1, float* __restrict__ dv1,
    float* __restrict__ f2, float* __restrict__ g2, float* __restrict__ dv2,
    float* __restrict__ gtfps, unsigned* __restrict__ sync,
    float* __restrict__ out) {
  __shared__ Lds L;
  const int blk = blockIdx.x;
  const int t = threadIdx.x;
  unsigned* cnt1 = &sync[0]; unsigned* gen1 = &sync[1];
  unsigned* cnt2 = &sync[2]; unsigned* gen2 = &sync[3];
  unsigned* fpsflag = &sync[4];            // [4],[5] per batch
  unsigned* done2 = &sync[6]; unsigned* chamdone = &sync[7];

  if (blk < 2) {                                       // ---------------- FPS
    fps_body(L, gt, gtfps, blk);
    signal_done(&fpsflag[blk]);
    return;
  }
  if (blk < 130) {                                     // ---------------- EMD2
    const int eb = blk - 2;
    const int b = eb >> 6, bxl = eb & 63;
    const int r0b = bxl * 64;
    const int iters = *itersPtr;
    const float* fb = fine + (size_t)b*4096*3;
    const float* gb = gt   + (size_t)b*4096*3;
    float* f2b = f2 + b*4096; float* g2b = g2 + b*4096; float* dv2b = dv2 + b*4096;
    for (int ph = 0; ph < 8; ++ph) {
      const int k = ph >> 1;
      if (k < iters) {
        if (!(ph & 1))
          emd_pass_512(fb, 4095, gb, 4095, g2b, f2b, 4096, LOGN2, k > 0, r0b,
                       L.emd.tyx, L.emd.tyy, L.emd.tyz, L.emd.tg);
        else
          emd_pass_512(gb, 4095, fb, 4095, f2b, g2b, 4096, LOGN2, 1, r0b,
                       L.emd.tyx, L.emd.tyy, L.emd.tyz, L.emd.tg);
      }
      gbar(cnt2, gen2, 128u);
    }
    emd_final_512(fb, 4095, gb, 4095, g2b, dv2b, 4096, iters > 0, r0b,
                  L.emd.tyx, L.emd.tyy, L.emd.tyz, L.emd.tg);
    signal_done(done2);
    return;
  }
  if (blk < 162) {                                     // ---------------- EMD1
    const int eb = blk - 130;
    const int b = eb >> 4, bxl = eb & 15;
    const int r0b = bxl * 64;
    const int iters = *itersPtr;
    const float* cb = coarse + (size_t)b*512*3;        // xtile == coarse with &511 wrap
    const float* pb = gtfps  + (size_t)b*1024*3;
    float* f1b = f1 + b*1024; float* g1b = g1 + b*1024; float* dv1b = dv1 + b*1024;
    waitcnt_ge(&fpsflag[b], 1u);                       // gtfps ready
    for (int ph = 0; ph < 8; ++ph) {
      const int k = ph >> 1;
      if (k < iters) {
        if (!(ph & 1))
          emd_pass_512(cb, 511, pb, 1023, g1b, f1b, 1024, LOGN1, k > 0, r0b,
                       L.emd.tyx, L.emd.tyy, L.emd.tyz, L.emd.tg);
        else
          emd_pass_512(pb, 1023, cb, 511, f1b, g1b, 1024, LOGN1, 1, r0b,
                       L.emd.tyx, L.emd.tyy, L.emd.tyz, L.emd.tg);
      }
      gbar(cnt1, gen1, 32u);
    }
    emd_final_512(cb, 511, pb, 1023, g1b, dv1b, 1024, iters > 0, r0b,
                  L.emd.tyx, L.emd.tyy, L.emd.tyz, L.emd.tg);
    gbar(cnt1, gen1, 32u);                             // dv1 complete
    if (bxl == 0) {                                    // one finalizer per batch
      waitcnt_ge(done2, 128u);                         // dv2 complete
      waitcnt_ge(chamdone, 50u);                       // chamA-D complete
      finalize_body(b, chamA, chamB, chamC, chamD, dv1, dv2, out, L.emd.tyx);
    }
    return;
  }
  if (blk < 212) {                                     // ---------------- chamfer
    const int cid = blk - 162;
    const float *q, *tp; float* om; int nq, nt, b, qx;
    if (cid < 16)      { b = cid>>3;        qx = cid&7; q = gt;     nq = 4096; tp = coarse; nt = 512;  om = chamA; }
    else if (cid < 18) { b = cid-16;        qx = 0;     q = coarse; nq = 512;  tp = gt;     nt = 4096; om = chamB; }
    else if (cid < 34) { int r = cid-18; b = r>>3; qx = r&7; q = gt;   nq = 4096; tp = fine; nt = 4096; om = chamC; }
    else               { int r = cid-34; b = r>>3; qx = r&7; q = fine; nq = 4096; tp = gt;   nt = 4096; om = chamD; }
    const int qi = qx*512 + t;
    const float* qp = q + (size_t)(b*nq + qi)*3;
    float qxv = qp[0], qyv = qp[1], qzv = qp[2];
    float m = 3.4e38f;
    for (int tt0 = 0; tt0 < nt; tt0 += 1024) {
      int chunk = min(1024, nt - tt0);
      __syncthreads();
      for (int i = t; i < chunk; i += 512) {
        const float* pp = tp + (size_t)(b*nt + tt0 + i)*3;
        L.ch.x[i] = pp[0]; L.ch.y[i] = pp[1]; L.ch.z[i] = pp[2];
      }
      __syncthreads();
      for (int i = 0; i < chunk; ++i) {
        float dx = qxv-L.ch.x[i], dy = qyv-L.ch.y[i], dz = qzv-L.ch.z[i];
        float d = dx*dx + dy*dy + dz*dz;
        m = fminf(m, d);
      }
    }
    om[b*nq + qi] = m;
    signal_done(chamdone);
    return;
  }
  // ---------------- output copies (grid-stride over 40 blocks) ----------------
  for (int i = (blk-212)*512 + t; i < 27648; i += 40*512)
    out[i] = (i < 3072) ? coarse[i] : fine[i - 3072];
}

extern "C" void kernel_launch(void* const* d_in, const int* in_sizes, int n_in,
                              void* d_out, int out_size, void* d_ws, size_t ws_size,
                              hipStream_t stream) {
  (void)in_sizes; (void)n_in; (void)out_size; (void)ws_size;
  const float* coarse = (const float*)d_in[0];
  const float* fine   = (const float*)d_in[1];
  const float* gt     = (const float*)d_in[2];
  const int*   iters  = (const int*)d_in[3];
  float* out = (float*)d_out;
  float* ws  = (float*)d_ws;

  float* chamA = ws + 0;        // 2*4096
  float* chamB = ws + 8192;     // 2*512
  float* chamC = ws + 9216;     // 2*4096
  float* chamD = ws + 17408;    // 2*4096
  float* f1    = ws + 25600;    // 2*1024
  float* g1    = ws + 27648;    // 2*1024
  float* dv1   = ws + 29696;    // 2*1024
  float* f2    = ws + 31744;    // 2*4096
  float* g2    = ws + 39936;    // 2*4096
  float* dv2   = ws + 48128;    // 2*4096
  float* gtfps = ws + 56320;    // 2*1024*3
  unsigned* sync = (unsigned*)(ws + 62464);  // 8 words

  init_sync<<<1, 64, 0, stream>>>(sync);
  everything<<<252, 512, 0, stream>>>(coarse, fine, gt, iters,
                                      chamA, chamB, chamC, chamD,
                                      f1, g1, dv1, f2, g2, dv2,
                                      gtfps, sync, out);
}